// Round 1
// baseline (44.356 us; speedup 1.0000x reference)
//
#include <hip/hip_runtime.h>

#define EPSF 1e-7f

__device__ __forceinline__ float rcp_fast(float x) { return __builtin_amdgcn_rcpf(x); }

// Kernel 1: x2[j] = ||x_j||^2
__global__ void x2_kernel(const float* __restrict__ x, float* __restrict__ x2, int N) {
    int j = blockIdx.x * blockDim.x + threadIdx.x;
    if (j < N) {
        const float4* row = reinterpret_cast<const float4*>(x + (size_t)j * 64);
        float s = 0.f;
#pragma unroll
        for (int c = 0; c < 16; ++c) {
            float4 v = row[c];
            s += v.x * v.x + v.y * v.y + v.z * v.z + v.w * v.w;
        }
        x2[j] = s;
    }
}

// Kernel 2: one block per row i. 256 threads: lane-pair (t, t^1) owns one j;
// h = t&1 selects d-half [h*32, h*32+32). Scalars s,t per pair; register acc.
__global__ __launch_bounds__(256) void agg_kernel(
    const float* __restrict__ x, const int* __restrict__ adj,
    const float* __restrict__ x2ws, float* __restrict__ out) {
    const int N = 1024, D = 64;
    const int i = blockIdx.x;
    const int t = threadIdx.x;
    const int jl = t >> 1;  // 0..127 within tile
    const int h = t & 1;    // d-half

    // xi chunk (32 floats) for this thread's d-half
    float xi[32];
    {
        const float4* p = reinterpret_cast<const float4*>(x + (size_t)i * D + h * 32);
#pragma unroll
        for (int c = 0; c < 8; ++c) {
            float4 v = p[c];
            xi[4 * c + 0] = v.x; xi[4 * c + 1] = v.y;
            xi[4 * c + 2] = v.z; xi[4 * c + 3] = v.w;
        }
    }
    const float x2i = x2ws[i];
    const float onemx2 = 1.0f - x2i;            // raw (1 - ||x||^2)
    const float onemx2c = fmaxf(onemx2, EPSF);  // clipped (= 2/lambda_x)

    float acc[32];
#pragma unroll
    for (int k = 0; k < 32; ++k) acc[k] = 0.f;
    float alpha = 0.f;

    for (int tile = 0; tile < 8; ++tile) {
        const int j = tile * 128 + jl;
        const int m = adj[(size_t)i * N + j];
        const float y2 = x2ws[j];
        float xj[32];
        const float4* p = reinterpret_cast<const float4*>(x + (size_t)j * D + h * 32);
#pragma unroll
        for (int c = 0; c < 8; ++c) {
            float4 v = p[c];
            xj[4 * c + 0] = v.x; xj[4 * c + 1] = v.y;
            xj[4 * c + 2] = v.z; xj[4 * c + 3] = v.w;
        }
        float dp = 0.f;
#pragma unroll
        for (int k = 0; k < 32; ++k) dp = fmaf(xi[k], xj[k], dp);
        const float dot = dp + __shfl_xor(dp, 1, 64);

        // u = (a*xi + b*xj), coefficients from mobius_add(-xi, xj)
        const float c1 = fmaf(-2.f, dot, 1.f);          // 1 - 2*dot
        const float A = c1 + y2;                        // 1 - 2*dot + y2
        const float den = fmaxf(fmaf(x2i, y2, c1), EPSF);
        const float rd = rcp_fast(den);
        const float a = -A * rd;
        const float b = onemx2 * rd;
        float un2 = a * a * x2i;
        un2 = fmaf(b * b, y2, un2);
        un2 = fmaf(2.f * a * b, dot, un2);
        un2 = fmaxf(un2, 0.f);
        float un = sqrtf(un2);
        un = fminf(fmaxf(un, EPSF), 1.0f - 1e-5f);
        const float ratio = (1.f + un) * rcp_fast(1.f - un);
        const float at = 0.34657359027997264f * __log2f(ratio);  // atanh(un)
        const float g = onemx2c * at * rcp_fast(un);
        float sv = g * a;
        float tv = g * b;
        if (!m) { sv = 0.f; tv = 0.f; }
        alpha += (h == 0) ? sv : 0.f;
#pragma unroll
        for (int k = 0; k < 32; ++k) acc[k] = fmaf(tv, xj[k], acc[k]);
    }

    // intra-wave reduce over j-lanes (bits 1..5); keep d-half (bit 0) separate
#pragma unroll
    for (int off = 2; off < 64; off <<= 1) {
#pragma unroll
        for (int k = 0; k < 32; ++k) acc[k] += __shfl_xor(acc[k], off, 64);
        alpha += __shfl_xor(alpha, off, 64);
    }

    __shared__ float lds_acc[4][64];
    __shared__ float lds_alpha[4];
    const int w = t >> 6, lane = t & 63;
    if (lane < 2) {  // lane0: h=0 total, lane1: h=1 total
#pragma unroll
        for (int k = 0; k < 32; ++k) lds_acc[w][h * 32 + k] = acc[k];
        if (lane == 0) lds_alpha[w] = alpha;
    }
    __syncthreads();

    if (t < 64) {
        const int d = t;
        float v = 0.f;
#pragma unroll
        for (int ww = 0; ww < 4; ++ww) v += lds_acc[ww][d];
        const float alph = lds_alpha[0] + lds_alpha[1] + lds_alpha[2] + lds_alpha[3];
        const float xid = x[(size_t)i * D + d];
        v = fmaf(alph, xid, v);

        // expmap(v, xi)
        float vn2 = v * v;
#pragma unroll
        for (int off = 1; off < 64; off <<= 1) vn2 += __shfl_xor(vn2, off, 64);
        const float vn = fmaxf(sqrtf(vn2), EPSF);
        const float arg = vn * rcp_fast(onemx2c);   // lambda*vn/2
        const float th = tanhf(arg);
        const float sec = th * rcp_fast(vn) * v;    // second[d]

        // mobius_add(xi, second)
        float xy = xid * sec;
        float y2p = sec * sec;
#pragma unroll
        for (int off = 1; off < 64; off <<= 1) {
            xy += __shfl_xor(xy, off, 64);
            y2p += __shfl_xor(y2p, off, 64);
        }
        const float numd = (1.f + 2.f * xy + y2p) * xid + onemx2 * sec;
        const float den2 = fmaxf(fmaf(x2i, y2p, 1.f + 2.f * xy), EPSF);
        out[(size_t)i * D + d] = numd * rcp_fast(den2);
    }
}

extern "C" void kernel_launch(void* const* d_in, const int* in_sizes, int n_in,
                              void* d_out, int out_size, void* d_ws, size_t ws_size,
                              hipStream_t stream) {
    const float* x = (const float*)d_in[0];
    const int* adj = (const int*)d_in[1];
    float* out = (float*)d_out;
    float* x2 = (float*)d_ws;
    const int N = 1024;

    hipLaunchKernelGGL(x2_kernel, dim3((N + 255) / 256), dim3(256), 0, stream, x, x2, N);
    hipLaunchKernelGGL(agg_kernel, dim3(N), dim3(256), 0, stream, x, adj, x2, out);
}